// Round 1
// baseline (5469.883 us; speedup 1.0000x reference)
//
#include <hip/hip_runtime.h>
#include <hip/hip_bf16.h>
#include <math.h>

// Problem constants
#define LSEQ 2048
#define DMODEL 1024
#define DINNER 2048
#define DSTATE 16
#define DCONV 4
#define DTRANK 64
#define RPROJ 96   // DTRANK + 2*DSTATE

__device__ __forceinline__ float softplusf(float x) {
    return (x > 20.f) ? x : log1pf(__expf(x));
}
__device__ __forceinline__ float siluf(float x) {
    return x / (1.f + __expf(-x));
}

// ---------------- LayerNorm: one block per row ----------------
__global__ __launch_bounds__(256) void ln_kernel(
    const float* __restrict__ x, const float* __restrict__ w,
    const float* __restrict__ b, float* __restrict__ out)
{
    __shared__ float s1[256], s2[256];
    const int row = blockIdx.x;
    const int tid = threadIdx.x;
    const float* xr = x + (size_t)row * DMODEL;
    float v[4];
    float s = 0.f, sq = 0.f;
#pragma unroll
    for (int k = 0; k < 4; k++) {
        v[k] = xr[k * 256 + tid];
        s += v[k];
        sq += v[k] * v[k];
    }
    s1[tid] = s; s2[tid] = sq;
    __syncthreads();
    for (int off = 128; off > 0; off >>= 1) {
        if (tid < off) { s1[tid] += s1[tid + off]; s2[tid] += s2[tid + off]; }
        __syncthreads();
    }
    const float mu = s1[0] * (1.f / DMODEL);
    const float var = s2[0] * (1.f / DMODEL) - mu * mu;
    const float rstd = rsqrtf(var + 1e-5f);
    float* orow = out + (size_t)row * DMODEL;
#pragma unroll
    for (int k = 0; k < 4; k++) {
        int i = k * 256 + tid;
        orow[i] = (v[k] - mu) * rstd * w[i] + b[i];
    }
}

// ---------------- Generic NT GEMM: C[M,N] = A[M,K] * W[N,K]^T ----------------
// mode 0: plain   mode 1: softplus(. + bias[n])   mode 2: . + resid[m,n]
#define BM 64
#define BN 64
#define BK 16
__global__ __launch_bounds__(256) void gemm_nt(
    const float* __restrict__ A, int lda,
    const float* __restrict__ W, int ldw,
    float* __restrict__ C, int ldc,
    int M, int N, int K,
    const float* __restrict__ bias,
    const float* __restrict__ resid,
    int mode)
{
    __shared__ float As[BK][BM];
    __shared__ float Ws[BK][BN];
    const int tid = threadIdx.x;
    const int row0 = blockIdx.y * BM;
    const int col0 = blockIdx.x * BN;
    const int lr = tid >> 2;          // 0..63
    const int lk = (tid & 3) << 2;    // 0,4,8,12
    const int tx = tid & 15;          // col group
    const int ty = tid >> 4;          // row group

    float acc[4][4] = {{0.f}};

    for (int kt = 0; kt < K; kt += BK) {
        // stage A tile (M,K always divisible by 64/16 in this problem)
        const float4 av = *(const float4*)(A + (size_t)(row0 + lr) * lda + kt + lk);
        As[lk + 0][lr] = av.x; As[lk + 1][lr] = av.y;
        As[lk + 2][lr] = av.z; As[lk + 3][lr] = av.w;
        // stage W tile with N guard
        float4 wv = make_float4(0.f, 0.f, 0.f, 0.f);
        const int wr = col0 + lr;
        if (wr < N) wv = *(const float4*)(W + (size_t)wr * ldw + kt + lk);
        Ws[lk + 0][lr] = wv.x; Ws[lk + 1][lr] = wv.y;
        Ws[lk + 2][lr] = wv.z; Ws[lk + 3][lr] = wv.w;
        __syncthreads();
#pragma unroll
        for (int k = 0; k < BK; k++) {
            const float4 a4 = *(const float4*)&As[k][ty * 4];
            const float4 w4 = *(const float4*)&Ws[k][tx * 4];
            acc[0][0] += a4.x * w4.x; acc[0][1] += a4.x * w4.y;
            acc[0][2] += a4.x * w4.z; acc[0][3] += a4.x * w4.w;
            acc[1][0] += a4.y * w4.x; acc[1][1] += a4.y * w4.y;
            acc[1][2] += a4.y * w4.z; acc[1][3] += a4.y * w4.w;
            acc[2][0] += a4.z * w4.x; acc[2][1] += a4.z * w4.y;
            acc[2][2] += a4.z * w4.z; acc[2][3] += a4.z * w4.w;
            acc[3][0] += a4.w * w4.x; acc[3][1] += a4.w * w4.y;
            acc[3][2] += a4.w * w4.z; acc[3][3] += a4.w * w4.w;
        }
        __syncthreads();
    }

    const int c = col0 + tx * 4;
    if (c >= N) return;  // N is always a multiple of 4; col tiles align
#pragma unroll
    for (int i = 0; i < 4; i++) {
        const int r = row0 + ty * 4 + i;
        float4 v = make_float4(acc[i][0], acc[i][1], acc[i][2], acc[i][3]);
        if (mode == 1) {
            v.x = softplusf(v.x + bias[c + 0]);
            v.y = softplusf(v.y + bias[c + 1]);
            v.z = softplusf(v.z + bias[c + 2]);
            v.w = softplusf(v.w + bias[c + 3]);
        } else if (mode == 2) {
            const float4 rv = *(const float4*)(resid + (size_t)r * ldc + c);
            v.x += rv.x; v.y += rv.y; v.z += rv.z; v.w += rv.w;
        }
        *(float4*)(C + (size_t)r * ldc + c) = v;
    }
}

// ---------------- Causal depthwise conv (k=4) + bias + silu ----------------
// reads xz[:, 0:DINNER] (row stride 2*DINNER), writes xc[L, DINNER]
__global__ __launch_bounds__(256) void conv_silu_kernel(
    const float* __restrict__ xz, const float* __restrict__ cw,
    const float* __restrict__ cb, float* __restrict__ xc)
{
    const int g = blockIdx.x * 256 + threadIdx.x;  // g < L*DINNER
    const int c = g & (DINNER - 1);
    const int t = g >> 11;  // DINNER = 2048
    float acc = cb[c];
#pragma unroll
    for (int k = 0; k < DCONV; k++) {
        const int tt = t - (DCONV - 1) + k;
        if (tt >= 0) acc += xz[(size_t)tt * (2 * DINNER) + c] * cw[c * DCONV + k];
    }
    xc[(size_t)t * DINNER + c] = siluf(acc);
}

// ---------------- Selective scan: one lane per channel ----------------
// y may alias dt (each (t,e) read before written by the same thread).
__global__ __launch_bounds__(256) void scan_kernel(
    const float* __restrict__ dt,    // [L, DINNER]
    const float* __restrict__ xc,    // [L, DINNER]
    const float* __restrict__ dbl,   // [L, RPROJ]; cols 64..79 = B, 80..95 = C
    const float* __restrict__ xz,    // [L, 2*DINNER]; z at cols DINNER..
    const float* __restrict__ A_log, // [DINNER, DSTATE]
    const float* __restrict__ Dp,    // [DINNER]
    float* __restrict__ y)           // [L, DINNER]
{
    const int e = blockIdx.x * 256 + threadIdx.x;
    float a[DSTATE];
#pragma unroll
    for (int n = 0; n < DSTATE; n++) a[n] = -__expf(A_log[(size_t)e * DSTATE + n]);
    float h[DSTATE];
#pragma unroll
    for (int n = 0; n < DSTATE; n++) h[n] = 0.f;
    const float dskip = Dp[e];

    __shared__ float sBC[64][32];
    for (int t0 = 0; t0 < LSEQ; t0 += 64) {
        __syncthreads();
        for (int i = threadIdx.x; i < 64 * 32; i += 256) {
            const int tl = i >> 5, j = i & 31;
            sBC[tl][j] = dbl[(size_t)(t0 + tl) * RPROJ + DTRANK + j];
        }
        __syncthreads();
        for (int tl = 0; tl < 64; tl++) {
            const int t = t0 + tl;
            const float dtv = dt[(size_t)t * DINNER + e];
            const float xcv = xc[(size_t)t * DINNER + e];
            const float du = dtv * xcv;
            float yv = 0.f;
#pragma unroll
            for (int n = 0; n < DSTATE; n++) {
                const float dA = __expf(dtv * a[n]);
                h[n] = dA * h[n] + du * sBC[tl][n];
                yv += h[n] * sBC[tl][16 + n];
            }
            const float zv = xz[(size_t)t * (2 * DINNER) + DINNER + e];
            yv = (yv + xcv * dskip) * siluf(zv);
            y[(size_t)t * DINNER + e] = yv;
        }
    }
}

extern "C" void kernel_launch(void* const* d_in, const int* in_sizes, int n_in,
                              void* d_out, int out_size, void* d_ws, size_t ws_size,
                              hipStream_t stream) {
    const float* x_in   = (const float*)d_in[0];
    const float* ln_w   = (const float*)d_in[1];
    const float* ln_b   = (const float*)d_in[2];
    const float* in_w   = (const float*)d_in[3];
    const float* conv_w = (const float*)d_in[4];
    const float* conv_b = (const float*)d_in[5];
    const float* xp_w   = (const float*)d_in[6];
    const float* dtp_w  = (const float*)d_in[7];
    const float* dtp_b  = (const float*)d_in[8];
    const float* A_log  = (const float*)d_in[9];
    const float* D_skip = (const float*)d_in[10];
    const float* out_w  = (const float*)d_in[11];
    const float* nf_w   = (const float*)d_in[12];
    const float* nf_b   = (const float*)d_in[13];
    float* out = (float*)d_out;

    float* w = (float*)d_ws;
    float* buf_x = w; w += (size_t)LSEQ * DMODEL;      // residual stream
    float* h_buf = w; w += (size_t)LSEQ * DMODEL;      // LN output
    float* xz    = w; w += (size_t)LSEQ * 2 * DINNER;  // in_proj out
    float* xc    = w; w += (size_t)LSEQ * DINNER;      // conv+silu out
    float* dbl   = w; w += (size_t)LSEQ * RPROJ;       // x_proj out
    float* dtb   = w; w += (size_t)LSEQ * DINNER;      // dt (y written in-place)

    for (int layer = 0; layer < 2; layer++) {
        const float* resid_src = (layer == 0) ? x_in : buf_x;
        // 1. LayerNorm
        ln_kernel<<<dim3(LSEQ), dim3(256), 0, stream>>>(
            resid_src, ln_w + layer * DMODEL, ln_b + layer * DMODEL, h_buf);
        // 2. in_proj: xz[L, 4096] = h[L,1024] * in_w[4096,1024]^T
        gemm_nt<<<dim3((2 * DINNER) / BN, LSEQ / BM), dim3(256), 0, stream>>>(
            h_buf, DMODEL, in_w + (size_t)layer * 2 * DINNER * DMODEL, DMODEL,
            xz, 2 * DINNER, LSEQ, 2 * DINNER, DMODEL, nullptr, nullptr, 0);
        // 3. conv + silu
        conv_silu_kernel<<<dim3((LSEQ * DINNER) / 256), dim3(256), 0, stream>>>(
            xz, conv_w + (size_t)layer * DINNER * DCONV, conv_b + layer * DINNER, xc);
        // 4. x_proj: dbl[L,96] = xc[L,2048] * xp_w[96,2048]^T
        gemm_nt<<<dim3((RPROJ + BN - 1) / BN, LSEQ / BM), dim3(256), 0, stream>>>(
            xc, DINNER, xp_w + (size_t)layer * RPROJ * DINNER, DINNER,
            dbl, RPROJ, LSEQ, RPROJ, DINNER, nullptr, nullptr, 0);
        // 5. dt_proj + softplus: dt[L,2048] = sp(dbl[:, :64] * dtp_w[2048,64]^T + b)
        gemm_nt<<<dim3(DINNER / BN, LSEQ / BM), dim3(256), 0, stream>>>(
            dbl, RPROJ, dtp_w + (size_t)layer * DINNER * DTRANK, DTRANK,
            dtb, DINNER, LSEQ, DINNER, DTRANK,
            dtp_b + layer * DINNER, nullptr, 1);
        // 6. selective scan (+ skip + z-gate); y overwrites dtb
        scan_kernel<<<dim3(DINNER / 256), dim3(256), 0, stream>>>(
            dtb, xc, dbl, xz,
            A_log + (size_t)layer * DINNER * DSTATE, D_skip + layer * DINNER, dtb);
        // 7. out_proj + residual: buf_x = y * out_w[1024,2048]^T + resid
        gemm_nt<<<dim3(DMODEL / BN, LSEQ / BM), dim3(256), 0, stream>>>(
            dtb, DINNER, out_w + (size_t)layer * DMODEL * DINNER, DINNER,
            buf_x, DMODEL, LSEQ, DMODEL, DINNER, nullptr, resid_src, 2);
    }
    // final LayerNorm -> d_out
    ln_kernel<<<dim3(LSEQ), dim3(256), 0, stream>>>(buf_x, nf_w, nf_b, out);
}

// Round 2
// 1501.912 us; speedup vs baseline: 3.6419x; 3.6419x over previous
//
#include <hip/hip_runtime.h>
#include <hip/hip_bf16.h>
#include <math.h>

// Problem constants
#define LSEQ 2048
#define DMODEL 1024
#define DINNER 2048
#define DSTATE 16
#define DCONV 4
#define DTRANK 64
#define RPROJ 96   // DTRANK + 2*DSTATE

// Chunked-scan decomposition
#define CHUNK 32
#define NCHUNK (LSEQ / CHUNK)   // 64

__device__ __forceinline__ float softplusf(float x) {
    return (x > 20.f) ? x : log1pf(__expf(x));
}
__device__ __forceinline__ float siluf(float x) {
    return x / (1.f + __expf(-x));
}

// ---------------- LayerNorm: one block per row ----------------
__global__ __launch_bounds__(256) void ln_kernel(
    const float* __restrict__ x, const float* __restrict__ w,
    const float* __restrict__ b, float* __restrict__ out)
{
    __shared__ float s1[256], s2[256];
    const int row = blockIdx.x;
    const int tid = threadIdx.x;
    const float* xr = x + (size_t)row * DMODEL;
    float v[4];
    float s = 0.f, sq = 0.f;
#pragma unroll
    for (int k = 0; k < 4; k++) {
        v[k] = xr[k * 256 + tid];
        s += v[k];
        sq += v[k] * v[k];
    }
    s1[tid] = s; s2[tid] = sq;
    __syncthreads();
    for (int off = 128; off > 0; off >>= 1) {
        if (tid < off) { s1[tid] += s1[tid + off]; s2[tid] += s2[tid + off]; }
        __syncthreads();
    }
    const float mu = s1[0] * (1.f / DMODEL);
    const float var = s2[0] * (1.f / DMODEL) - mu * mu;
    const float rstd = rsqrtf(var + 1e-5f);
    float* orow = out + (size_t)row * DMODEL;
#pragma unroll
    for (int k = 0; k < 4; k++) {
        int i = k * 256 + tid;
        orow[i] = (v[k] - mu) * rstd * w[i] + b[i];
    }
}

// ---------------- Generic NT GEMM: C[M,N] = A[M,K] * W[N,K]^T ----------------
// mode 0: plain   mode 1: softplus(. + bias[n])   mode 2: . + resid[m,n]
#define BM 64
#define BN 64
#define BK 16
__global__ __launch_bounds__(256) void gemm_nt(
    const float* __restrict__ A, int lda,
    const float* __restrict__ W, int ldw,
    float* __restrict__ C, int ldc,
    int M, int N, int K,
    const float* __restrict__ bias,
    const float* __restrict__ resid,
    int mode)
{
    __shared__ float As[BK][BM];
    __shared__ float Ws[BK][BN];
    const int tid = threadIdx.x;
    const int row0 = blockIdx.y * BM;
    const int col0 = blockIdx.x * BN;
    const int lr = tid >> 2;          // 0..63
    const int lk = (tid & 3) << 2;    // 0,4,8,12
    const int tx = tid & 15;          // col group
    const int ty = tid >> 4;          // row group

    float acc[4][4] = {{0.f}};

    for (int kt = 0; kt < K; kt += BK) {
        const float4 av = *(const float4*)(A + (size_t)(row0 + lr) * lda + kt + lk);
        As[lk + 0][lr] = av.x; As[lk + 1][lr] = av.y;
        As[lk + 2][lr] = av.z; As[lk + 3][lr] = av.w;
        float4 wv = make_float4(0.f, 0.f, 0.f, 0.f);
        const int wr = col0 + lr;
        if (wr < N) wv = *(const float4*)(W + (size_t)wr * ldw + kt + lk);
        Ws[lk + 0][lr] = wv.x; Ws[lk + 1][lr] = wv.y;
        Ws[lk + 2][lr] = wv.z; Ws[lk + 3][lr] = wv.w;
        __syncthreads();
#pragma unroll
        for (int k = 0; k < BK; k++) {
            const float4 a4 = *(const float4*)&As[k][ty * 4];
            const float4 w4 = *(const float4*)&Ws[k][tx * 4];
            acc[0][0] += a4.x * w4.x; acc[0][1] += a4.x * w4.y;
            acc[0][2] += a4.x * w4.z; acc[0][3] += a4.x * w4.w;
            acc[1][0] += a4.y * w4.x; acc[1][1] += a4.y * w4.y;
            acc[1][2] += a4.y * w4.z; acc[1][3] += a4.y * w4.w;
            acc[2][0] += a4.z * w4.x; acc[2][1] += a4.z * w4.y;
            acc[2][2] += a4.z * w4.z; acc[2][3] += a4.z * w4.w;
            acc[3][0] += a4.w * w4.x; acc[3][1] += a4.w * w4.y;
            acc[3][2] += a4.w * w4.z; acc[3][3] += a4.w * w4.w;
        }
        __syncthreads();
    }

    const int c = col0 + tx * 4;
    if (c >= N) return;
#pragma unroll
    for (int i = 0; i < 4; i++) {
        const int r = row0 + ty * 4 + i;
        float4 v = make_float4(acc[i][0], acc[i][1], acc[i][2], acc[i][3]);
        if (mode == 1) {
            v.x = softplusf(v.x + bias[c + 0]);
            v.y = softplusf(v.y + bias[c + 1]);
            v.z = softplusf(v.z + bias[c + 2]);
            v.w = softplusf(v.w + bias[c + 3]);
        } else if (mode == 2) {
            const float4 rv = *(const float4*)(resid + (size_t)r * ldc + c);
            v.x += rv.x; v.y += rv.y; v.z += rv.z; v.w += rv.w;
        }
        *(float4*)(C + (size_t)r * ldc + c) = v;
    }
}

// ---------------- Causal depthwise conv (k=4) + bias + silu ----------------
__global__ __launch_bounds__(256) void conv_silu_kernel(
    const float* __restrict__ xz, const float* __restrict__ cw,
    const float* __restrict__ cb, float* __restrict__ xc)
{
    const int g = blockIdx.x * 256 + threadIdx.x;
    const int c = g & (DINNER - 1);
    const int t = g >> 11;
    float acc = cb[c];
#pragma unroll
    for (int k = 0; k < DCONV; k++) {
        const int tt = t - (DCONV - 1) + k;
        if (tt >= 0) acc += xz[(size_t)tt * (2 * DINNER) + c] * cw[c * DCONV + k];
    }
    xc[(size_t)t * DINNER + c] = siluf(acc);
}

// ============ Chunked selective scan ============
// h_t = exp(dt_t*a_n) h_{t-1} + dt_t*xc_t*B_t[n];  y_t = <h_t, C_t>
// Chunk decay prod = exp(a_n * sum(dt)) -> summaries are S[c,e,n] + sumdt[c,e].

// pass1: per-chunk local scan from h=0. Writes S[c][n][e] and sumdt[c][e].
__global__ __launch_bounds__(256) void scan_pass1(
    const float* __restrict__ dt,    // [L, DINNER]
    const float* __restrict__ xc,    // [L, DINNER]
    const float* __restrict__ dbl,   // [L, RPROJ]
    const float* __restrict__ A_log, // [DINNER, DSTATE]
    float* __restrict__ S,           // [NCHUNK][DSTATE][DINNER]
    float* __restrict__ sumdt)       // [NCHUNK][DINNER]
{
    const int e = blockIdx.x * 256 + threadIdx.x;
    const int c = blockIdx.y;
    float a[DSTATE];
#pragma unroll
    for (int n = 0; n < DSTATE; n++) a[n] = -__expf(A_log[(size_t)e * DSTATE + n]);
    float h[DSTATE];
#pragma unroll
    for (int n = 0; n < DSTATE; n++) h[n] = 0.f;
    float sd = 0.f;

    __shared__ float sBC[CHUNK][32];
    for (int i = threadIdx.x; i < CHUNK * 32; i += 256) {
        const int tl = i >> 5, j = i & 31;
        sBC[tl][j] = dbl[(size_t)(c * CHUNK + tl) * RPROJ + DTRANK + j];
    }
    __syncthreads();

    for (int tl = 0; tl < CHUNK; tl++) {
        const int t = c * CHUNK + tl;
        const float dtv = dt[(size_t)t * DINNER + e];
        const float du = dtv * xc[(size_t)t * DINNER + e];
        sd += dtv;
#pragma unroll
        for (int n = 0; n < DSTATE; n++) {
            const float dA = __expf(dtv * a[n]);
            h[n] = dA * h[n] + du * sBC[tl][n];
        }
    }
    sumdt[(size_t)c * DINNER + e] = sd;
#pragma unroll
    for (int n = 0; n < DSTATE; n++)
        S[((size_t)c * DSTATE + n) * DINNER + e] = h[n];
}

// pass2: sequential combine over chunks; rewrite S in place with carry-IN
// (exclusive scan). One thread per (n,e).
__global__ __launch_bounds__(256) void scan_pass2(
    const float* __restrict__ A_log,
    const float* __restrict__ sumdt,
    float* __restrict__ S)
{
    const int idx = blockIdx.x * 256 + threadIdx.x;   // 0..32767
    const int e = idx & (DINNER - 1);
    const int n = idx >> 11;
    const float a = -__expf(A_log[(size_t)e * DSTATE + n]);
    float H = 0.f;
    for (int c = 0; c < NCHUNK; c++) {
        const size_t off = ((size_t)c * DSTATE + n) * DINNER + e;
        const float tmp = S[off];
        S[off] = H;
        const float P = __expf(a * sumdt[(size_t)c * DINNER + e]);
        H = P * H + tmp;
    }
}

// pass3: re-run chunk-local scan seeded with carry-in; produce gated y.
// y may alias dt (same thread reads (t,e) before writing it).
__global__ __launch_bounds__(256) void scan_pass3(
    const float* __restrict__ dt,
    const float* __restrict__ xc,
    const float* __restrict__ dbl,
    const float* __restrict__ xz,    // z at cols DINNER..
    const float* __restrict__ A_log,
    const float* __restrict__ Dp,
    const float* __restrict__ S,     // carry-in [NCHUNK][DSTATE][DINNER]
    float* __restrict__ y)
{
    const int e = blockIdx.x * 256 + threadIdx.x;
    const int c = blockIdx.y;
    float a[DSTATE];
#pragma unroll
    for (int n = 0; n < DSTATE; n++) a[n] = -__expf(A_log[(size_t)e * DSTATE + n]);
    float h[DSTATE];
#pragma unroll
    for (int n = 0; n < DSTATE; n++)
        h[n] = S[((size_t)c * DSTATE + n) * DINNER + e];
    const float dskip = Dp[e];

    __shared__ float sBC[CHUNK][32];
    for (int i = threadIdx.x; i < CHUNK * 32; i += 256) {
        const int tl = i >> 5, j = i & 31;
        sBC[tl][j] = dbl[(size_t)(c * CHUNK + tl) * RPROJ + DTRANK + j];
    }
    __syncthreads();

    for (int tl = 0; tl < CHUNK; tl++) {
        const int t = c * CHUNK + tl;
        const float dtv = dt[(size_t)t * DINNER + e];
        const float xcv = xc[(size_t)t * DINNER + e];
        const float du = dtv * xcv;
        float yv = 0.f;
#pragma unroll
        for (int n = 0; n < DSTATE; n++) {
            const float dA = __expf(dtv * a[n]);
            h[n] = dA * h[n] + du * sBC[tl][n];
            yv += h[n] * sBC[tl][16 + n];
        }
        const float zv = xz[(size_t)t * (2 * DINNER) + DINNER + e];
        yv = (yv + xcv * dskip) * siluf(zv);
        y[(size_t)t * DINNER + e] = yv;
    }
}

extern "C" void kernel_launch(void* const* d_in, const int* in_sizes, int n_in,
                              void* d_out, int out_size, void* d_ws, size_t ws_size,
                              hipStream_t stream) {
    const float* x_in   = (const float*)d_in[0];
    const float* ln_w   = (const float*)d_in[1];
    const float* ln_b   = (const float*)d_in[2];
    const float* in_w   = (const float*)d_in[3];
    const float* conv_w = (const float*)d_in[4];
    const float* conv_b = (const float*)d_in[5];
    const float* xp_w   = (const float*)d_in[6];
    const float* dtp_w  = (const float*)d_in[7];
    const float* dtp_b  = (const float*)d_in[8];
    const float* A_log  = (const float*)d_in[9];
    const float* D_skip = (const float*)d_in[10];
    const float* out_w  = (const float*)d_in[11];
    const float* nf_w   = (const float*)d_in[12];
    const float* nf_b   = (const float*)d_in[13];
    float* out = (float*)d_out;

    float* w = (float*)d_ws;
    float* buf_x = w; w += (size_t)LSEQ * DMODEL;      // residual stream
    float* h_buf = w; w += (size_t)LSEQ * DMODEL;      // LN output
    float* xz    = w; w += (size_t)LSEQ * 2 * DINNER;  // in_proj out
    float* xc    = w; w += (size_t)LSEQ * DINNER;      // conv+silu out
    float* dbl   = w; w += (size_t)LSEQ * RPROJ;       // x_proj out
    float* dtb   = w; w += (size_t)LSEQ * DINNER;      // dt (y written in-place)
    float* Sbuf  = w; w += (size_t)NCHUNK * DSTATE * DINNER;  // chunk summaries / carry-in
    float* sumdt = w; w += (size_t)NCHUNK * DINNER;    // per-chunk dt sums

    for (int layer = 0; layer < 2; layer++) {
        const float* resid_src = (layer == 0) ? x_in : buf_x;
        // 1. LayerNorm
        ln_kernel<<<dim3(LSEQ), dim3(256), 0, stream>>>(
            resid_src, ln_w + layer * DMODEL, ln_b + layer * DMODEL, h_buf);
        // 2. in_proj: xz[L, 4096] = h[L,1024] * in_w[4096,1024]^T
        gemm_nt<<<dim3((2 * DINNER) / BN, LSEQ / BM), dim3(256), 0, stream>>>(
            h_buf, DMODEL, in_w + (size_t)layer * 2 * DINNER * DMODEL, DMODEL,
            xz, 2 * DINNER, LSEQ, 2 * DINNER, DMODEL, nullptr, nullptr, 0);
        // 3. conv + silu
        conv_silu_kernel<<<dim3((LSEQ * DINNER) / 256), dim3(256), 0, stream>>>(
            xz, conv_w + (size_t)layer * DINNER * DCONV, conv_b + layer * DINNER, xc);
        // 4. x_proj: dbl[L,96] = xc[L,2048] * xp_w[96,2048]^T
        gemm_nt<<<dim3((RPROJ + BN - 1) / BN, LSEQ / BM), dim3(256), 0, stream>>>(
            xc, DINNER, xp_w + (size_t)layer * RPROJ * DINNER, DINNER,
            dbl, RPROJ, LSEQ, RPROJ, DINNER, nullptr, nullptr, 0);
        // 5. dt_proj + softplus
        gemm_nt<<<dim3(DINNER / BN, LSEQ / BM), dim3(256), 0, stream>>>(
            dbl, RPROJ, dtp_w + (size_t)layer * DINNER * DTRANK, DTRANK,
            dtb, DINNER, LSEQ, DINNER, DTRANK,
            dtp_b + layer * DINNER, nullptr, 1);
        // 6. chunked selective scan (+ skip + z-gate); y overwrites dtb
        const float* Al = A_log + (size_t)layer * DINNER * DSTATE;
        scan_pass1<<<dim3(DINNER / 256, NCHUNK), dim3(256), 0, stream>>>(
            dtb, xc, dbl, Al, Sbuf, sumdt);
        scan_pass2<<<dim3((DINNER * DSTATE) / 256), dim3(256), 0, stream>>>(
            Al, sumdt, Sbuf);
        scan_pass3<<<dim3(DINNER / 256, NCHUNK), dim3(256), 0, stream>>>(
            dtb, xc, dbl, xz, Al, D_skip + layer * DINNER, Sbuf, dtb);
        // 7. out_proj + residual
        gemm_nt<<<dim3(DMODEL / BN, LSEQ / BM), dim3(256), 0, stream>>>(
            dtb, DINNER, out_w + (size_t)layer * DMODEL * DINNER, DINNER,
            buf_x, DMODEL, LSEQ, DMODEL, DINNER, nullptr, resid_src, 2);
    }
    // final LayerNorm -> d_out
    ln_kernel<<<dim3(LSEQ), dim3(256), 0, stream>>>(buf_x, nf_w, nf_b, out);
}

// Round 3
// 530.144 us; speedup vs baseline: 10.3177x; 2.8330x over previous
//
#include <hip/hip_runtime.h>
#include <hip/hip_bf16.h>
#include <math.h>

// Problem constants
#define LSEQ 2048
#define DMODEL 1024
#define DINNER 2048
#define DSTATE 16
#define DCONV 4
#define DTRANK 64
#define RPROJ 96   // DTRANK + 2*DSTATE

// Chunked-scan decomposition
#define CHUNK 32
#define NCHUNK (LSEQ / CHUNK)   // 64

typedef __attribute__((ext_vector_type(8))) short bf16x8;
typedef __attribute__((ext_vector_type(4))) float f32x4;

__device__ __forceinline__ float softplusf(float x) {
    return (x > 20.f) ? x : log1pf(__expf(x));
}
__device__ __forceinline__ float siluf(float x) {
    return x / (1.f + __expf(-x));
}
// f32 -> bf16 RTNE
__device__ __forceinline__ short f2bf(float f) {
    union { float f; unsigned u; } v; v.f = f;
    unsigned r = v.u + 0x7FFFu + ((v.u >> 16) & 1u);
    return (short)(r >> 16);
}

// ---------------- f32 -> bf16 bulk convert (n % 8 == 0) ----------------
__global__ __launch_bounds__(256) void cvt_bf16(
    const float* __restrict__ s, short* __restrict__ d, int n)
{
    const int i = (blockIdx.x * 256 + threadIdx.x) * 8;
    if (i >= n) return;
    const float4 a = *(const float4*)(s + i);
    const float4 b = *(const float4*)(s + i + 4);
    alignas(16) short h[8];
    h[0] = f2bf(a.x); h[1] = f2bf(a.y); h[2] = f2bf(a.z); h[3] = f2bf(a.w);
    h[4] = f2bf(b.x); h[5] = f2bf(b.y); h[6] = f2bf(b.z); h[7] = f2bf(b.w);
    *(uint4*)(d + i) = *(const uint4*)h;
}

// ---------------- LayerNorm: one block per row; optional f32/bf16 outs ----
__global__ __launch_bounds__(256) void ln_kernel(
    const float* __restrict__ x, const float* __restrict__ w,
    const float* __restrict__ b, float* __restrict__ outf,
    short* __restrict__ outb)
{
    __shared__ float s1[256], s2[256];
    const int row = blockIdx.x;
    const int tid = threadIdx.x;
    const float* xr = x + (size_t)row * DMODEL;
    float v[4];
    float s = 0.f, sq = 0.f;
#pragma unroll
    for (int k = 0; k < 4; k++) {
        v[k] = xr[k * 256 + tid];
        s += v[k];
        sq += v[k] * v[k];
    }
    s1[tid] = s; s2[tid] = sq;
    __syncthreads();
    for (int off = 128; off > 0; off >>= 1) {
        if (tid < off) { s1[tid] += s1[tid + off]; s2[tid] += s2[tid + off]; }
        __syncthreads();
    }
    const float mu = s1[0] * (1.f / DMODEL);
    const float var = s2[0] * (1.f / DMODEL) - mu * mu;
    const float rstd = rsqrtf(var + 1e-5f);
#pragma unroll
    for (int k = 0; k < 4; k++) {
        const int i = k * 256 + tid;
        const float o = (v[k] - mu) * rstd * w[i] + b[i];
        if (outf) outf[(size_t)row * DMODEL + i] = o;
        if (outb) outb[(size_t)row * DMODEL + i] = f2bf(o);
    }
}

// ---------------- bf16 MFMA NT GEMM: C[M,N] = A[M,K] * W[N,K]^T -----------
// m97-style: 128-row tile, BN_T in {64,128}, BK=32, global_load_lds staging.
// MODE 0: plain store   MODE 2: += resid
template<int BN_T, int MODE>
__global__ __launch_bounds__(256) void gemm_mfma(
    const short* __restrict__ A,   // [M,K] bf16
    const short* __restrict__ W,   // [N,K] bf16
    float* __restrict__ C, int ldc,
    int M, int N, int K,
    const float* __restrict__ resid)
{
    constexpr int BK = 32;
    constexpr int HN = BN_T / 2;      // wave col span
    constexpr int NJ = BN_T / 32;     // 16x16 frags per wave in N
    constexpr int WISS = (BN_T * BK * 2) / 4096;  // W staging issues (1 or 2)
    __shared__ alignas(16) short As[128 * BK];
    __shared__ alignas(16) short Ws[BN_T * BK];

    const int tid = threadIdx.x;
    const int lane = tid & 63;
    const int w = tid >> 6;
    const int wr = w >> 1, wc = w & 1;
    const int row0 = blockIdx.y * 128;
    const int col0 = blockIdx.x * BN_T;

    const int srow = tid >> 2;            // staging row within 64-row group
    const int skch = (tid & 3) * 8;       // staging k element offset

    f32x4 acc[4][NJ];
#pragma unroll
    for (int i = 0; i < 4; i++)
#pragma unroll
        for (int j = 0; j < NJ; j++) acc[i][j] = (f32x4)0.f;

    const int lrow = lane & 15;
    const int lk = (lane >> 4) * 8;

    for (int kt = 0; kt < K; kt += BK) {
        __syncthreads();
        // stage A tile: 128 rows x 32 k (bf16), 2 issues of 4 KB
#pragma unroll
        for (int j = 0; j < 2; j++) {
            const short* gp = A + (size_t)(row0 + j * 64 + srow) * K + kt + skch;
            short* lp = As + j * 2048 + w * 512;   // wave-uniform LDS base
            __builtin_amdgcn_global_load_lds(
                (const __attribute__((address_space(1))) void*)gp,
                (__attribute__((address_space(3))) void*)lp, 16, 0, 0);
        }
        // stage W tile
#pragma unroll
        for (int j = 0; j < WISS; j++) {
            const int wrow = col0 + j * 64 + srow;
            const short* gp = W + (size_t)wrow * K + kt + skch;
            short* lp = Ws + j * 2048 + w * 512;
            if (wrow < N)
                __builtin_amdgcn_global_load_lds(
                    (const __attribute__((address_space(1))) void*)gp,
                    (__attribute__((address_space(3))) void*)lp, 16, 0, 0);
        }
        __syncthreads();

        bf16x8 af[4], bfr[NJ];
#pragma unroll
        for (int i = 0; i < 4; i++)
            af[i] = *(const bf16x8*)&As[(wr * 64 + i * 16 + lrow) * BK + lk];
#pragma unroll
        for (int j = 0; j < NJ; j++)
            bfr[j] = *(const bf16x8*)&Ws[(wc * HN + j * 16 + lrow) * BK + lk];
#pragma unroll
        for (int i = 0; i < 4; i++)
#pragma unroll
            for (int j = 0; j < NJ; j++)
                acc[i][j] = __builtin_amdgcn_mfma_f32_16x16x32_bf16(
                    af[i], bfr[j], acc[i][j], 0, 0, 0);
    }

    // epilogue: C/D layout col=lane&15, row=(lane>>4)*4+reg
    const int rbase = row0 + wr * 64;
    const int cbase = col0 + wc * HN;
#pragma unroll
    for (int i = 0; i < 4; i++) {
#pragma unroll
        for (int j = 0; j < NJ; j++) {
            const int gcol = cbase + j * 16 + lrow;
            if (gcol < N) {
#pragma unroll
                for (int r = 0; r < 4; r++) {
                    const int grow = rbase + i * 16 + (lane >> 4) * 4 + r;
                    float v = acc[i][j][r];
                    if (MODE == 2) v += resid[(size_t)grow * ldc + gcol];
                    C[(size_t)grow * ldc + gcol] = v;
                }
            }
        }
    }
}

// ---------------- f32 NT GEMM (kept for dt_proj, K=64) ----------------
// mode 1: softplus(. + bias[n])
#define BM 64
#define BN 64
#define BK16 16
__global__ __launch_bounds__(256) void gemm_nt(
    const float* __restrict__ A, int lda,
    const float* __restrict__ W, int ldw,
    float* __restrict__ C, int ldc,
    int M, int N, int K,
    const float* __restrict__ bias)
{
    __shared__ float As[BK16][BM];
    __shared__ float Ws[BK16][BN];
    const int tid = threadIdx.x;
    const int row0 = blockIdx.y * BM;
    const int col0 = blockIdx.x * BN;
    const int lr = tid >> 2;
    const int lk = (tid & 3) << 2;
    const int tx = tid & 15;
    const int ty = tid >> 4;

    float acc[4][4] = {{0.f}};

    for (int kt = 0; kt < K; kt += BK16) {
        const float4 av = *(const float4*)(A + (size_t)(row0 + lr) * lda + kt + lk);
        As[lk + 0][lr] = av.x; As[lk + 1][lr] = av.y;
        As[lk + 2][lr] = av.z; As[lk + 3][lr] = av.w;
        const float4 wv = *(const float4*)(W + (size_t)(col0 + lr) * ldw + kt + lk);
        Ws[lk + 0][lr] = wv.x; Ws[lk + 1][lr] = wv.y;
        Ws[lk + 2][lr] = wv.z; Ws[lk + 3][lr] = wv.w;
        __syncthreads();
#pragma unroll
        for (int k = 0; k < BK16; k++) {
            const float4 a4 = *(const float4*)&As[k][ty * 4];
            const float4 w4 = *(const float4*)&Ws[k][tx * 4];
            acc[0][0] += a4.x * w4.x; acc[0][1] += a4.x * w4.y;
            acc[0][2] += a4.x * w4.z; acc[0][3] += a4.x * w4.w;
            acc[1][0] += a4.y * w4.x; acc[1][1] += a4.y * w4.y;
            acc[1][2] += a4.y * w4.z; acc[1][3] += a4.y * w4.w;
            acc[2][0] += a4.z * w4.x; acc[2][1] += a4.z * w4.y;
            acc[2][2] += a4.z * w4.z; acc[2][3] += a4.z * w4.w;
            acc[3][0] += a4.w * w4.x; acc[3][1] += a4.w * w4.y;
            acc[3][2] += a4.w * w4.z; acc[3][3] += a4.w * w4.w;
        }
        __syncthreads();
    }

    const int c = col0 + tx * 4;
#pragma unroll
    for (int i = 0; i < 4; i++) {
        const int r = row0 + ty * 4 + i;
        float4 v = make_float4(acc[i][0], acc[i][1], acc[i][2], acc[i][3]);
        v.x = softplusf(v.x + bias[c + 0]);
        v.y = softplusf(v.y + bias[c + 1]);
        v.z = softplusf(v.z + bias[c + 2]);
        v.w = softplusf(v.w + bias[c + 3]);
        *(float4*)(C + (size_t)r * ldc + c) = v;
    }
}

// ---------------- Causal depthwise conv (k=4) + bias + silu ----------------
__global__ __launch_bounds__(256) void conv_silu_kernel(
    const float* __restrict__ xz, const float* __restrict__ cw,
    const float* __restrict__ cb, float* __restrict__ xc,
    short* __restrict__ xcb)
{
    const int g = blockIdx.x * 256 + threadIdx.x;
    const int c = g & (DINNER - 1);
    const int t = g >> 11;
    float acc = cb[c];
#pragma unroll
    for (int k = 0; k < DCONV; k++) {
        const int tt = t - (DCONV - 1) + k;
        if (tt >= 0) acc += xz[(size_t)tt * (2 * DINNER) + c] * cw[c * DCONV + k];
    }
    const float o = siluf(acc);
    xc[(size_t)t * DINNER + c] = o;
    xcb[(size_t)t * DINNER + c] = f2bf(o);
}

// ============ Chunked selective scan ============
__global__ __launch_bounds__(256) void scan_pass1(
    const float* __restrict__ dt,
    const float* __restrict__ xc,
    const float* __restrict__ dbl,
    const float* __restrict__ A_log,
    float* __restrict__ S,           // [NCHUNK][DSTATE][DINNER]
    float* __restrict__ sumdt)       // [NCHUNK][DINNER]
{
    const int e = blockIdx.x * 256 + threadIdx.x;
    const int c = blockIdx.y;
    float a[DSTATE];
#pragma unroll
    for (int n = 0; n < DSTATE; n++) a[n] = -__expf(A_log[(size_t)e * DSTATE + n]);
    float h[DSTATE];
#pragma unroll
    for (int n = 0; n < DSTATE; n++) h[n] = 0.f;
    float sd = 0.f;

    __shared__ float sBC[CHUNK][32];
    for (int i = threadIdx.x; i < CHUNK * 32; i += 256) {
        const int tl = i >> 5, j = i & 31;
        sBC[tl][j] = dbl[(size_t)(c * CHUNK + tl) * RPROJ + DTRANK + j];
    }
    __syncthreads();

    for (int tl = 0; tl < CHUNK; tl++) {
        const int t = c * CHUNK + tl;
        const float dtv = dt[(size_t)t * DINNER + e];
        const float du = dtv * xc[(size_t)t * DINNER + e];
        sd += dtv;
#pragma unroll
        for (int n = 0; n < DSTATE; n++) {
            const float dA = __expf(dtv * a[n]);
            h[n] = dA * h[n] + du * sBC[tl][n];
        }
    }
    sumdt[(size_t)c * DINNER + e] = sd;
#pragma unroll
    for (int n = 0; n < DSTATE; n++)
        S[((size_t)c * DSTATE + n) * DINNER + e] = h[n];
}

__global__ __launch_bounds__(256) void scan_pass2(
    const float* __restrict__ A_log,
    const float* __restrict__ sumdt,
    float* __restrict__ S)
{
    const int idx = blockIdx.x * 256 + threadIdx.x;
    const int e = idx & (DINNER - 1);
    const int n = idx >> 11;
    const float a = -__expf(A_log[(size_t)e * DSTATE + n]);
    float H = 0.f;
    for (int c = 0; c < NCHUNK; c++) {
        const size_t off = ((size_t)c * DSTATE + n) * DINNER + e;
        const float tmp = S[off];
        S[off] = H;
        const float P = __expf(a * sumdt[(size_t)c * DINNER + e]);
        H = P * H + tmp;
    }
}

// pass3 writes bf16 y (consumed only by out_proj MFMA GEMM)
__global__ __launch_bounds__(256) void scan_pass3(
    const float* __restrict__ dt,
    const float* __restrict__ xc,
    const float* __restrict__ dbl,
    const float* __restrict__ xz,    // z at cols DINNER..
    const float* __restrict__ A_log,
    const float* __restrict__ Dp,
    const float* __restrict__ S,
    short* __restrict__ yb)
{
    const int e = blockIdx.x * 256 + threadIdx.x;
    const int c = blockIdx.y;
    float a[DSTATE];
#pragma unroll
    for (int n = 0; n < DSTATE; n++) a[n] = -__expf(A_log[(size_t)e * DSTATE + n]);
    float h[DSTATE];
#pragma unroll
    for (int n = 0; n < DSTATE; n++)
        h[n] = S[((size_t)c * DSTATE + n) * DINNER + e];
    const float dskip = Dp[e];

    __shared__ float sBC[CHUNK][32];
    for (int i = threadIdx.x; i < CHUNK * 32; i += 256) {
        const int tl = i >> 5, j = i & 31;
        sBC[tl][j] = dbl[(size_t)(c * CHUNK + tl) * RPROJ + DTRANK + j];
    }
    __syncthreads();

    for (int tl = 0; tl < CHUNK; tl++) {
        const int t = c * CHUNK + tl;
        const float dtv = dt[(size_t)t * DINNER + e];
        const float xcv = xc[(size_t)t * DINNER + e];
        const float du = dtv * xcv;
        float yv = 0.f;
#pragma unroll
        for (int n = 0; n < DSTATE; n++) {
            const float dA = __expf(dtv * a[n]);
            h[n] = dA * h[n] + du * sBC[tl][n];
            yv += h[n] * sBC[tl][16 + n];
        }
        const float zv = xz[(size_t)t * (2 * DINNER) + DINNER + e];
        yv = (yv + xcv * dskip) * siluf(zv);
        yb[(size_t)t * DINNER + e] = f2bf(yv);
    }
}

extern "C" void kernel_launch(void* const* d_in, const int* in_sizes, int n_in,
                              void* d_out, int out_size, void* d_ws, size_t ws_size,
                              hipStream_t stream) {
    const float* x_in   = (const float*)d_in[0];
    const float* ln_w   = (const float*)d_in[1];
    const float* ln_b   = (const float*)d_in[2];
    const float* in_w   = (const float*)d_in[3];
    const float* conv_w = (const float*)d_in[4];
    const float* conv_b = (const float*)d_in[5];
    const float* xp_w   = (const float*)d_in[6];
    const float* dtp_w  = (const float*)d_in[7];
    const float* dtp_b  = (const float*)d_in[8];
    const float* A_log  = (const float*)d_in[9];
    const float* D_skip = (const float*)d_in[10];
    const float* out_w  = (const float*)d_in[11];
    const float* nf_w   = (const float*)d_in[12];
    const float* nf_b   = (const float*)d_in[13];
    float* out = (float*)d_out;

    float* w = (float*)d_ws;
    float* buf_x = w; w += (size_t)LSEQ * DMODEL;
    float* xz    = w; w += (size_t)LSEQ * 2 * DINNER;
    float* xc    = w; w += (size_t)LSEQ * DINNER;
    float* dbl   = w; w += (size_t)LSEQ * RPROJ;
    float* dtb   = w; w += (size_t)LSEQ * DINNER;
    float* Sbuf  = w; w += (size_t)NCHUNK * DSTATE * DINNER;
    float* sumdt = w; w += (size_t)NCHUNK * DINNER;
    // bf16 buffers (allocated in float units, 2 shorts per float)
    short* h_bf    = (short*)w; w += (size_t)LSEQ * DMODEL / 2;
    short* xc_bf   = (short*)w; w += (size_t)LSEQ * DINNER / 2;
    short* y_bf    = (short*)w; w += (size_t)LSEQ * DINNER / 2;
    short* in_w_bf  = (short*)w; w += (size_t)2 * (2 * DINNER) * DMODEL / 2;
    short* xp_w_bf  = (short*)w; w += (size_t)2 * RPROJ * DINNER / 2;
    short* out_w_bf = (short*)w; w += (size_t)2 * DMODEL * DINNER / 2;

    // weight conversions (all layers at once)
    {
        const int n1 = 2 * (2 * DINNER) * DMODEL;   // 8.4M
        cvt_bf16<<<dim3(n1 / (256 * 8)), dim3(256), 0, stream>>>(in_w, in_w_bf, n1);
        const int n2 = 2 * RPROJ * DINNER;          // 393K
        cvt_bf16<<<dim3(n2 / (256 * 8)), dim3(256), 0, stream>>>(xp_w, xp_w_bf, n2);
        const int n3 = 2 * DMODEL * DINNER;         // 4.2M
        cvt_bf16<<<dim3(n3 / (256 * 8)), dim3(256), 0, stream>>>(out_w, out_w_bf, n3);
    }

    for (int layer = 0; layer < 2; layer++) {
        const float* resid_src = (layer == 0) ? x_in : buf_x;
        // 1. LayerNorm -> bf16
        ln_kernel<<<dim3(LSEQ), dim3(256), 0, stream>>>(
            resid_src, ln_w + layer * DMODEL, ln_b + layer * DMODEL,
            nullptr, h_bf);
        // 2. in_proj (bf16 MFMA): xz[L,4096] = h[L,1024] * in_w[4096,1024]^T
        gemm_mfma<128, 0><<<dim3((2 * DINNER) / 128, LSEQ / 128), dim3(256), 0, stream>>>(
            h_bf, in_w_bf + (size_t)layer * 2 * DINNER * DMODEL,
            xz, 2 * DINNER, LSEQ, 2 * DINNER, DMODEL, nullptr);
        // 3. conv + silu -> f32 + bf16
        conv_silu_kernel<<<dim3((LSEQ * DINNER) / 256), dim3(256), 0, stream>>>(
            xz, conv_w + (size_t)layer * DINNER * DCONV, conv_b + layer * DINNER,
            xc, xc_bf);
        // 4. x_proj (bf16 MFMA): dbl[L,96] = xc[L,2048] * xp_w[96,2048]^T
        gemm_mfma<64, 0><<<dim3((RPROJ + 63) / 64, LSEQ / 128), dim3(256), 0, stream>>>(
            xc_bf, xp_w_bf + (size_t)layer * RPROJ * DINNER,
            dbl, RPROJ, LSEQ, RPROJ, DINNER, nullptr);
        // 5. dt_proj + softplus (f32, K=64)
        gemm_nt<<<dim3(DINNER / BN, LSEQ / BM), dim3(256), 0, stream>>>(
            dbl, RPROJ, dtp_w + (size_t)layer * DINNER * DTRANK, DTRANK,
            dtb, DINNER, LSEQ, DINNER, DTRANK, dtp_b + layer * DINNER);
        // 6. chunked selective scan (+ skip + z-gate) -> y_bf
        const float* Al = A_log + (size_t)layer * DINNER * DSTATE;
        scan_pass1<<<dim3(DINNER / 256, NCHUNK), dim3(256), 0, stream>>>(
            dtb, xc, dbl, Al, Sbuf, sumdt);
        scan_pass2<<<dim3((DINNER * DSTATE) / 256), dim3(256), 0, stream>>>(
            Al, sumdt, Sbuf);
        scan_pass3<<<dim3(DINNER / 256, NCHUNK), dim3(256), 0, stream>>>(
            dtb, xc, dbl, xz, Al, D_skip + layer * DINNER, Sbuf, y_bf);
        // 7. out_proj (bf16 MFMA) + residual
        gemm_mfma<64, 2><<<dim3(DMODEL / 64, LSEQ / 128), dim3(256), 0, stream>>>(
            y_bf, out_w_bf + (size_t)layer * DMODEL * DINNER,
            buf_x, DMODEL, LSEQ, DMODEL, DINNER, resid_src);
    }
    // final LayerNorm -> d_out (f32)
    ln_kernel<<<dim3(LSEQ), dim3(256), 0, stream>>>(buf_x, nf_w, nf_b, out, nullptr);
}